// Round 5
// baseline (362.287 us; speedup 1.0000x reference)
//
#include <hip/hip_runtime.h>
#include <hip/hip_bf16.h>
#include <math.h>

#define DIM 1024
#define HID 2048
#define NEXP 8
#define NTOK 1024   // B*T
#define TOPK 2

typedef __attribute__((ext_vector_type(4))) float f32x4;
typedef __attribute__((ext_vector_type(8))) short bf16x8;
typedef __attribute__((ext_vector_type(4))) short bf16x4;

__device__ inline short bf1(float f) {
    __hip_bfloat16 b = __float2bfloat16(f);
    union { __hip_bfloat16 b; short s; } u; u.b = b; return u.s;
}
__device__ inline bf16x4 cvt4(f32x4 v) {
    bf16x4 r;
#pragma unroll
    for (int i = 0; i < 4; ++i) r[i] = bf1(v[i]);
    return r;
}
__device__ inline bf16x8 cat8(bf16x4 lo, bf16x4 hi) {
    bf16x8 r;
#pragma unroll
    for (int i = 0; i < 4; ++i) { r[i] = lo[i]; r[i + 4] = hi[i]; }
    return r;
}

// ---------------- x -> bf16 pre-convert ----------------
__global__ __launch_bounds__(256) void xcvt_kernel(const float* __restrict__ x, __hip_bfloat16* __restrict__ xb)
{
    int i = blockIdx.x * 256 + threadIdx.x;
    f32x4 v = *(const f32x4*)(x + (size_t)i * 4);
    *(bf16x4*)(xb + (size_t)i * 4) = cvt4(v);
}

// ---------------- router ----------------
__global__ __launch_bounds__(64) void router_kernel(
    const float* __restrict__ x, const float* __restrict__ rw,
    int* __restrict__ counts, int* __restrict__ slot_list, float* __restrict__ w_list)
{
    int t = blockIdx.x;
    int lane = threadIdx.x;
    const float* xr = x + (size_t)t * DIM;
    float acc[NEXP];
#pragma unroll
    for (int e = 0; e < NEXP; ++e) acc[e] = 0.f;
    for (int d = lane; d < DIM; d += 64) {
        float xv = xr[d];
#pragma unroll
        for (int e = 0; e < NEXP; ++e) acc[e] += xv * rw[e * DIM + d];
    }
#pragma unroll
    for (int off = 32; off > 0; off >>= 1) {
#pragma unroll
        for (int e = 0; e < NEXP; ++e) acc[e] += __shfl_down(acc[e], off, 64);
    }
    if (lane == 0) {
        int i1 = 0;
#pragma unroll
        for (int e = 1; e < NEXP; ++e) if (acc[e] > acc[i1]) i1 = e;
        int i2 = -1;
#pragma unroll
        for (int e = 0; e < NEXP; ++e) {
            if (e == i1) continue;
            if (i2 < 0 || acc[e] > acc[i2]) i2 = e;
        }
        float w1 = 1.f / (1.f + expf(acc[i2] - acc[i1]));
        float w2 = 1.f - w1;
        int p1 = atomicAdd(&counts[i1], 1);
        slot_list[i1 * NTOK + p1] = t * 2 + 0;
        w_list[i1 * NTOK + p1] = w1;
        int p2 = atomicAdd(&counts[i2], 1);
        slot_list[i2 * NTOK + p2] = t * 2 + 1;
        w_list[i2 * NTOK + p2] = w2;
    }
}

// ---------------- gate+up: barrier-free, LDS-free, reg-fragment MFMA ----------------
// 512 blocks: (p in [0,256) = e*32+hb64) x (z in {0,1}); z-twins share an XCD (bid&7).
// Wave wn owns 16 output cols; A-fragments per-lane from xb (L2); B from f32 weights, cvt in regs.
__global__ __launch_bounds__(256) void gateup_mfma(
    const __hip_bfloat16* __restrict__ xb, const float* __restrict__ wg, const float* __restrict__ wu,
    const int* __restrict__ counts, const int* __restrict__ slot_list, const float* __restrict__ w_list,
    const __hip_bfloat16* __restrict__ zrow, __hip_bfloat16* __restrict__ h_buf)
{
    int bid = blockIdx.x;
    int pl = bid & 7, s = bid >> 3;
    int z = s & 1, ph = s >> 1;
    int p = (ph << 3) + pl;              // 0..255
    int e = p >> 5;
    int hbase = (p & 31) * 64;

    int n_e = counts[e];
    if (n_e == 0) return;
    const int* sl = slot_list + e * NTOK;
    const float* wl = w_list + e * NTOK;

    int tid = threadIdx.x;
    int lane = tid & 63;
    int wn = tid >> 6;                   // wave -> 16-col strip
    int fr = lane & 15, fq = lane >> 4;

    // per-lane weight row pointers (output col = hbase + wn*16 + fr), K-offset fq*8
    const float* gp = wg + (size_t)e * HID * DIM + (size_t)(hbase + wn * 16 + fr) * DIM + fq * 8;
    const float* up = wu + (size_t)e * HID * DIM + (size_t)(hbase + wn * 16 + fr) * DIM + fq * 8;

    for (int m0 = z * 128; m0 < n_e; m0 += 256) {
        int rows = n_e - m0; if (rows > 128) rows = 128;

        // per-lane A row bases (token rows gathered via slot list); OOB rows -> zero page
        const __hip_bfloat16* ap[8];
#pragma unroll
        for (int ms = 0; ms < 8; ++ms) {
            int r = ms * 16 + fr;
            ap[ms] = (r < rows) ? (xb + (size_t)(sl[m0 + r] >> 1) * DIM + fq * 8) : (zrow + fq * 8);
        }

        f32x4 accg[8], accu[8];
#pragma unroll
        for (int ms = 0; ms < 8; ++ms) { accg[ms] = (f32x4)(0.f); accu[ms] = (f32x4)(0.f); }

        // prefetch step 0 weights (4x f32x4 per matrix: (kk,half))
        f32x4 gpre[4], upre[4];
#pragma unroll
        for (int q2 = 0; q2 < 4; ++q2) {
            gpre[q2] = *(const f32x4*)(gp + (q2 >> 1) * 32 + (q2 & 1) * 4);
            upre[q2] = *(const f32x4*)(up + (q2 >> 1) * 32 + (q2 & 1) * 4);
        }

#pragma unroll 1
        for (int t = 0; t < DIM / 64; ++t) {
            bf16x8 bg[2], bu[2];
#pragma unroll
            for (int kk = 0; kk < 2; ++kk) {
                bg[kk] = cat8(cvt4(gpre[2 * kk]), cvt4(gpre[2 * kk + 1]));
                bu[kk] = cat8(cvt4(upre[2 * kk]), cvt4(upre[2 * kk + 1]));
            }
            if (t + 1 < DIM / 64) {
                int ko = (t + 1) * 64;
#pragma unroll
                for (int q2 = 0; q2 < 4; ++q2) {
                    gpre[q2] = *(const f32x4*)(gp + ko + (q2 >> 1) * 32 + (q2 & 1) * 4);
                    upre[q2] = *(const f32x4*)(up + ko + (q2 >> 1) * 32 + (q2 & 1) * 4);
                }
            }
#pragma unroll
            for (int kk = 0; kk < 2; ++kk) {
                int ao = t * 64 + kk * 32;
#pragma unroll
                for (int ms = 0; ms < 8; ++ms) {
                    bf16x8 a = *(const bf16x8*)(ap[ms] + ao);
                    accg[ms] = __builtin_amdgcn_mfma_f32_16x16x32_bf16(a, bg[kk], accg[ms], 0, 0, 0);
                    accu[ms] = __builtin_amdgcn_mfma_f32_16x16x32_bf16(a, bu[kk], accu[ms], 0, 0, 0);
                }
            }
        }

        // epilogue: h = w * silu(g) * u -> bf16 (D: row = ms*16 + fq*4 + reg, col = wn*16 + fr)
#pragma unroll
        for (int ms = 0; ms < 8; ++ms) {
#pragma unroll
            for (int reg = 0; reg < 4; ++reg) {
                int r = ms * 16 + fq * 4 + reg;
                if (r < rows) {
                    int slot = sl[m0 + r];
                    float w = wl[m0 + r];
                    float g = accg[ms][reg], u = accu[ms][reg];
                    float h = w * (g / (1.f + expf(-g))) * u;
                    h_buf[(size_t)slot * HID + hbase + wn * 16 + fr] = __float2bfloat16(h);
                }
            }
        }
    }
}

// ---------------- down: barrier-free, LDS-free ----------------
// 512 blocks: (q in [0,128) = e*16+db64) x (z in {0..3}); z-quads share an XCD.
__global__ __launch_bounds__(256) void down_mfma(
    const __hip_bfloat16* __restrict__ h_buf, const float* __restrict__ wd,
    const int* __restrict__ counts, const int* __restrict__ slot_list,
    const __hip_bfloat16* __restrict__ zrow, float* __restrict__ ybuf)
{
    int bid = blockIdx.x;
    int pl = bid & 7, s = bid >> 3;
    int z = s & 3, qh = s >> 2;
    int q = (qh << 3) + pl;              // 0..127
    int e = q >> 4;
    int dbase = (q & 15) * 64;

    int n_e = counts[e];
    if (n_e == 0) return;
    const int* sl = slot_list + e * NTOK;

    int tid = threadIdx.x;
    int lane = tid & 63;
    int wn = tid >> 6;
    int fr = lane & 15, fq = lane >> 4;

    const float* wp = wd + (size_t)e * DIM * HID + (size_t)(dbase + wn * 16 + fr) * HID + fq * 8;

    for (int m0 = z * 64; m0 < n_e; m0 += 256) {
        int rows = n_e - m0; if (rows > 64) rows = 64;

        const __hip_bfloat16* ap[4];
#pragma unroll
        for (int ms = 0; ms < 4; ++ms) {
            int r = ms * 16 + fr;
            ap[ms] = (r < rows) ? (h_buf + (size_t)sl[m0 + r] * HID + fq * 8) : (zrow + fq * 8);
        }

        f32x4 acc[4];
#pragma unroll
        for (int ms = 0; ms < 4; ++ms) acc[ms] = (f32x4)(0.f);

        f32x4 wpre[4];
#pragma unroll
        for (int q2 = 0; q2 < 4; ++q2)
            wpre[q2] = *(const f32x4*)(wp + (q2 >> 1) * 32 + (q2 & 1) * 4);

#pragma unroll 1
        for (int t = 0; t < HID / 64; ++t) {
            bf16x8 b[2];
#pragma unroll
            for (int kk = 0; kk < 2; ++kk)
                b[kk] = cat8(cvt4(wpre[2 * kk]), cvt4(wpre[2 * kk + 1]));
            if (t + 1 < HID / 64) {
                int ko = (t + 1) * 64;
#pragma unroll
                for (int q2 = 0; q2 < 4; ++q2)
                    wpre[q2] = *(const f32x4*)(wp + ko + (q2 >> 1) * 32 + (q2 & 1) * 4);
            }
#pragma unroll
            for (int kk = 0; kk < 2; ++kk) {
                int ao = t * 64 + kk * 32;
#pragma unroll
                for (int ms = 0; ms < 4; ++ms) {
                    bf16x8 a = *(const bf16x8*)(ap[ms] + ao);
                    acc[ms] = __builtin_amdgcn_mfma_f32_16x16x32_bf16(a, b[kk], acc[ms], 0, 0, 0);
                }
            }
        }

#pragma unroll
        for (int ms = 0; ms < 4; ++ms) {
#pragma unroll
            for (int reg = 0; reg < 4; ++reg) {
                int r = ms * 16 + fq * 4 + reg;
                if (r < rows) {
                    int slot = sl[m0 + r];
                    ybuf[(size_t)slot * DIM + dbase + wn * 16 + fr] = acc[ms][reg];
                }
            }
        }
    }
}

// ---------------- combine ----------------
__global__ __launch_bounds__(256) void combine_kernel(const float* __restrict__ ybuf, float* __restrict__ out)
{
    int i = blockIdx.x * 256 + threadIdx.x;
    int t = i >> 8;
    int c = i & 255;
    const float4* ya = (const float4*)(ybuf + (size_t)(2 * t) * DIM) + c;
    const float4* yb = (const float4*)(ybuf + (size_t)(2 * t + 1) * DIM) + c;
    float4 a = *ya, b = *yb, r;
    r.x = a.x + b.x; r.y = a.y + b.y; r.z = a.z + b.z; r.w = a.w + b.w;
    ((float4*)(out + (size_t)t * DIM))[c] = r;
}

extern "C" void kernel_launch(void* const* d_in, const int* in_sizes, int n_in,
                              void* d_out, int out_size, void* d_ws, size_t ws_size,
                              hipStream_t stream) {
    const float* x  = (const float*)d_in[0];
    const float* rw = (const float*)d_in[1];
    const float* wg = (const float*)d_in[2];
    const float* wu = (const float*)d_in[3];
    const float* wd = (const float*)d_in[4];
    float* out = (float*)d_out;

    char* ws = (char*)d_ws;
    int* counts            = (int*)ws;                                   // 256 B
    int* slot_list         = (int*)(ws + 256);                           // 32 KB
    float* w_list          = (float*)(ws + 256 + NEXP * NTOK * 4);       // 32 KB
    __hip_bfloat16* xb     = (__hip_bfloat16*)(ws + 256 + 2 * NEXP * NTOK * 4);       // 2 MB
    __hip_bfloat16* h_buf  = (__hip_bfloat16*)((char*)xb + (size_t)NTOK * DIM * 2);   // 8 MB
    float* ybuf            = (float*)((char*)h_buf + (size_t)NTOK * TOPK * HID * 2);  // 8 MB
    __hip_bfloat16* zrow   = (__hip_bfloat16*)((char*)ybuf + (size_t)NTOK * TOPK * DIM * 4); // 4 KB zeros

    hipMemsetAsync(counts, 0, NEXP * sizeof(int), stream);
    hipMemsetAsync(zrow, 0, HID * sizeof(__hip_bfloat16), stream);
    xcvt_kernel<<<NTOK * DIM / 4 / 256, 256, 0, stream>>>(x, xb);
    router_kernel<<<NTOK, 64, 0, stream>>>(x, rw, counts, slot_list, w_list);
    gateup_mfma<<<512, 256, 0, stream>>>(xb, wg, wu, counts, slot_list, w_list, zrow, h_buf);
    down_mfma<<<512, 256, 0, stream>>>(h_buf, wd, counts, slot_list, zrow, ybuf);
    combine_kernel<<<NTOK * DIM / 4 / 256, 256, 0, stream>>>(ybuf, out);
}

// Round 6
// 152.753 us; speedup vs baseline: 2.3717x; 2.3717x over previous
//
#include <hip/hip_runtime.h>
#include <hip/hip_bf16.h>
#include <math.h>

#define DIM 1024
#define HID 2048
#define NEXP 8
#define NTOK 1024   // B*T
#define TOPK 2

typedef __attribute__((ext_vector_type(4))) float f32x4;
typedef __attribute__((ext_vector_type(8))) short bf16x8;
typedef __attribute__((ext_vector_type(4))) short bf16x4;

__device__ inline short bf1(float f) {
    union { __hip_bfloat16 b; short s; } u; u.b = __float2bfloat16(f); return u.s;
}
__device__ inline bf16x4 cvt4(f32x4 v) {
    bf16x4 r;
#pragma unroll
    for (int i = 0; i < 4; ++i) r[i] = bf1(v[i]);
    return r;
}
__device__ inline bf16x8 cat8(bf16x4 lo, bf16x4 hi) {
    bf16x8 r;
#pragma unroll
    for (int i = 0; i < 4; ++i) { r[i] = lo[i]; r[i + 4] = hi[i]; }
    return r;
}

// ---------------- router (fused with x->bf16 convert) ----------------
__global__ __launch_bounds__(64) void router_kernel(
    const float* __restrict__ x, const float* __restrict__ rw,
    __hip_bfloat16* __restrict__ xb,
    int* __restrict__ counts, int* __restrict__ slot_list, float* __restrict__ w_list)
{
    int t = blockIdx.x;
    int lane = threadIdx.x;
    const float* xr = x + (size_t)t * DIM;
    f32x4 xv[4];
#pragma unroll
    for (int qq = 0; qq < 4; ++qq) xv[qq] = *(const f32x4*)(xr + qq * 256 + lane * 4);
#pragma unroll
    for (int qq = 0; qq < 4; ++qq)
        *(bf16x4*)(xb + (size_t)t * DIM + qq * 256 + lane * 4) = cvt4(xv[qq]);

    float acc[NEXP];
#pragma unroll
    for (int e = 0; e < NEXP; ++e) {
        const float* rwe = rw + e * DIM;
        f32x4 s4 = (f32x4)(0.f);
#pragma unroll
        for (int qq = 0; qq < 4; ++qq) {
            f32x4 wv = *(const f32x4*)(rwe + qq * 256 + lane * 4);
            s4 += xv[qq] * wv;
        }
        acc[e] = s4[0] + s4[1] + s4[2] + s4[3];
    }
#pragma unroll
    for (int off = 32; off > 0; off >>= 1) {
#pragma unroll
        for (int e = 0; e < NEXP; ++e) acc[e] += __shfl_down(acc[e], off, 64);
    }
    if (lane == 0) {
        int i1 = 0;
#pragma unroll
        for (int e = 1; e < NEXP; ++e) if (acc[e] > acc[i1]) i1 = e;
        int i2 = -1;
#pragma unroll
        for (int e = 0; e < NEXP; ++e) {
            if (e == i1) continue;
            if (i2 < 0 || acc[e] > acc[i2]) i2 = e;
        }
        float w1 = 1.f / (1.f + expf(acc[i2] - acc[i1]));   // softmax renorm over top-2
        float w2 = 1.f - w1;
        int p1 = atomicAdd(&counts[i1], 1);
        slot_list[i1 * NTOK + p1] = t * 2 + 0;
        w_list[i1 * NTOK + p1] = w1;
        int p2 = atomicAdd(&counts[i2], 1);
        slot_list[i2 * NTOK + p2] = t * 2 + 1;
        w_list[i2 * NTOK + p2] = w2;
    }
}

// ---------------- gate+up grouped MFMA GEMM ----------------
// 64x64x64 tile, swizzled unpadded LDS (48KB -> 3 blocks/CU), single barrier/step,
// 2-deep register prefetch. grid 1024 = (p in [0,256)=e*32+hb) x (z in [0,4));
// bid = (p&7) + 8*(z + 4*(p>>3)) keeps z-replicas on one XCD (bid mod 8 fixed).
__global__ __launch_bounds__(256) void gateup_mfma(
    const __hip_bfloat16* __restrict__ xb, const float* __restrict__ wg,
    const float* __restrict__ wu, const int* __restrict__ counts,
    const int* __restrict__ slot_list, const float* __restrict__ w_list,
    const __hip_bfloat16* __restrict__ zrow, __hip_bfloat16* __restrict__ h_buf)
{
    __shared__ short Xs[2][64 * 64];
    __shared__ short Gs[2][64 * 64];
    __shared__ short Us[2][64 * 64];

    int bid = blockIdx.x;
    int pl = bid & 7, sfold = bid >> 3;
    int z = sfold & 3, ph = sfold >> 2;
    int p = (ph << 3) | pl;              // 0..255
    int e = p >> 5;
    int hbase = (p & 31) * 64;

    int n_e = counts[e];
    if (n_e == 0) return;
    const int* sl = slot_list + e * NTOK;
    const float* wl = w_list + e * NTOK;
    const float* WG = wg + (size_t)e * HID * DIM;
    const float* WU = wu + (size_t)e * HID * DIM;

    int tid = threadIdx.x;
    int lane = tid & 63;
    int wn = tid >> 6;                   // wave -> 16-col strip
    int fr = lane & 15, fq = lane >> 4;

    int r2 = tid >> 3;                   // staging row 0..31 (and +32)
    int j = tid & 7;                     // 16B chunk in row
    int sw = (j ^ (r2 & 7)) * 8;         // XOR chunk swizzle (same for r2+32)

    const float* g0 = WG + (size_t)(hbase + r2) * DIM + j * 8;
    const float* g1 = g0 + (size_t)32 * DIM;
    const float* u0 = WU + (size_t)(hbase + r2) * DIM + j * 8;
    const float* u1 = u0 + (size_t)32 * DIM;

    for (int m0 = z * 64; m0 < n_e; m0 += 256) {
        int rows = n_e - m0; if (rows > 64) rows = 64;
        const __hip_bfloat16* x0 = (r2 < rows) ? xb + (size_t)(sl[m0 + r2] >> 1) * DIM + j * 8 : zrow + j * 8;
        const __hip_bfloat16* x1 = (r2 + 32 < rows) ? xb + (size_t)(sl[m0 + r2 + 32] >> 1) * DIM + j * 8 : zrow + j * 8;

        f32x4 accg[4], accu[4];
#pragma unroll
        for (int ms = 0; ms < 4; ++ms) { accg[ms] = (f32x4)(0.f); accu[ms] = (f32x4)(0.f); }

        bf16x8 sx[2][2];
        f32x4 sg[2][4], su[2][4];
#pragma unroll
        for (int st = 0; st < 2; ++st) {
            int ko = st * 64;
            sx[st][0] = *(const bf16x8*)(x0 + ko);
            sx[st][1] = *(const bf16x8*)(x1 + ko);
            sg[st][0] = *(const f32x4*)(g0 + ko);
            sg[st][1] = *(const f32x4*)(g0 + ko + 4);
            sg[st][2] = *(const f32x4*)(g1 + ko);
            sg[st][3] = *(const f32x4*)(g1 + ko + 4);
            su[st][0] = *(const f32x4*)(u0 + ko);
            su[st][1] = *(const f32x4*)(u0 + ko + 4);
            su[st][2] = *(const f32x4*)(u1 + ko);
            su[st][3] = *(const f32x4*)(u1 + ko + 4);
        }

#pragma unroll 1
        for (int tt = 0; tt < DIM / 64; tt += 2) {
#pragma unroll
            for (int half = 0; half < 2; ++half) {
                // write stage -> LDS[half] (waits on its own loads via vmcnt)
                *(bf16x8*)&Xs[half][r2 * 64 + sw] = sx[half][0];
                *(bf16x8*)&Xs[half][(r2 + 32) * 64 + sw] = sx[half][1];
                *(bf16x8*)&Gs[half][r2 * 64 + sw] = cat8(cvt4(sg[half][0]), cvt4(sg[half][1]));
                *(bf16x8*)&Gs[half][(r2 + 32) * 64 + sw] = cat8(cvt4(sg[half][2]), cvt4(sg[half][3]));
                *(bf16x8*)&Us[half][r2 * 64 + sw] = cat8(cvt4(su[half][0]), cvt4(su[half][1]));
                *(bf16x8*)&Us[half][(r2 + 32) * 64 + sw] = cat8(cvt4(su[half][2]), cvt4(su[half][3]));
                // prefetch step t+2 (2-step lead ~ covers HBM latency)
                int k2 = (tt + half + 2) * 64;
                if (k2 < DIM) {
                    sx[half][0] = *(const bf16x8*)(x0 + k2);
                    sx[half][1] = *(const bf16x8*)(x1 + k2);
                    sg[half][0] = *(const f32x4*)(g0 + k2);
                    sg[half][1] = *(const f32x4*)(g0 + k2 + 4);
                    sg[half][2] = *(const f32x4*)(g1 + k2);
                    sg[half][3] = *(const f32x4*)(g1 + k2 + 4);
                    su[half][0] = *(const f32x4*)(u0 + k2);
                    su[half][1] = *(const f32x4*)(u0 + k2 + 4);
                    su[half][2] = *(const f32x4*)(u1 + k2);
                    su[half][3] = *(const f32x4*)(u1 + k2 + 4);
                }
                __syncthreads();
                // compute on LDS[half]
#pragma unroll
                for (int kk = 0; kk < 2; ++kk) {
                    int co = ((kk * 4 + fq) ^ (fr & 7)) * 8;
                    bf16x8 bg = *(const bf16x8*)&Gs[half][(wn * 16 + fr) * 64 + co];
                    bf16x8 bu = *(const bf16x8*)&Us[half][(wn * 16 + fr) * 64 + co];
#pragma unroll
                    for (int ms = 0; ms < 4; ++ms) {
                        bf16x8 a = *(const bf16x8*)&Xs[half][(ms * 16 + fr) * 64 + co];
                        accg[ms] = __builtin_amdgcn_mfma_f32_16x16x32_bf16(a, bg, accg[ms], 0, 0, 0);
                        accu[ms] = __builtin_amdgcn_mfma_f32_16x16x32_bf16(a, bu, accu[ms], 0, 0, 0);
                    }
                }
            }
        }

        // epilogue: h = w * silu(g) * u -> bf16 (D row = ms*16+fq*4+reg, col = wn*16+fr)
#pragma unroll
        for (int ms = 0; ms < 4; ++ms) {
#pragma unroll
            for (int reg = 0; reg < 4; ++reg) {
                int r = ms * 16 + fq * 4 + reg;
                if (r < rows) {
                    int slot = sl[m0 + r];
                    float w = wl[m0 + r];
                    float g = accg[ms][reg], u = accu[ms][reg];
                    float h = w * (g / (1.f + expf(-g))) * u;
                    h_buf[(size_t)slot * HID + hbase + wn * 16 + fr] = __float2bfloat16(h);
                }
            }
        }
    }
}

// ---------------- down grouped MFMA GEMM: y[pair] = h[pair] @ Wd^T ----------------
// grid 512 = (q in [0,128)=e*16+db) x (z in [0,4)); bid = (q&7)+8*(z+4*(q>>3)).
__global__ __launch_bounds__(256) void down_mfma(
    const __hip_bfloat16* __restrict__ h_buf, const float* __restrict__ wd,
    const int* __restrict__ counts, const int* __restrict__ slot_list,
    const __hip_bfloat16* __restrict__ zrow, float* __restrict__ ybuf)
{
    __shared__ short Hs[2][64 * 64];
    __shared__ short Ws[2][64 * 64];

    int bid = blockIdx.x;
    int pl = bid & 7, sfold = bid >> 3;
    int z = sfold & 3, qh = sfold >> 2;
    int q = (qh << 3) | pl;              // 0..127
    int e = q >> 4;
    int dbase = (q & 15) * 64;

    int n_e = counts[e];
    if (n_e == 0) return;
    const int* sl = slot_list + e * NTOK;
    const float* WD = wd + (size_t)e * DIM * HID;

    int tid = threadIdx.x;
    int lane = tid & 63;
    int wn = tid >> 6;
    int fr = lane & 15, fq = lane >> 4;

    int r2 = tid >> 3;
    int j = tid & 7;
    int sw = (j ^ (r2 & 7)) * 8;

    const float* w0 = WD + (size_t)(dbase + r2) * HID + j * 8;
    const float* w1 = w0 + (size_t)32 * HID;

    for (int m0 = z * 64; m0 < n_e; m0 += 256) {
        int rows = n_e - m0; if (rows > 64) rows = 64;
        const __hip_bfloat16* h0 = (r2 < rows) ? h_buf + (size_t)sl[m0 + r2] * HID + j * 8 : zrow + j * 8;
        const __hip_bfloat16* h1 = (r2 + 32 < rows) ? h_buf + (size_t)sl[m0 + r2 + 32] * HID + j * 8 : zrow + j * 8;

        f32x4 acc[4];
#pragma unroll
        for (int ms = 0; ms < 4; ++ms) acc[ms] = (f32x4)(0.f);

        bf16x8 sh[2][2];
        f32x4 sd[2][4];
#pragma unroll
        for (int st = 0; st < 2; ++st) {
            int ko = st * 64;
            sh[st][0] = *(const bf16x8*)(h0 + ko);
            sh[st][1] = *(const bf16x8*)(h1 + ko);
            sd[st][0] = *(const f32x4*)(w0 + ko);
            sd[st][1] = *(const f32x4*)(w0 + ko + 4);
            sd[st][2] = *(const f32x4*)(w1 + ko);
            sd[st][3] = *(const f32x4*)(w1 + ko + 4);
        }

#pragma unroll 1
        for (int tt = 0; tt < HID / 64; tt += 2) {
#pragma unroll
            for (int half = 0; half < 2; ++half) {
                *(bf16x8*)&Hs[half][r2 * 64 + sw] = sh[half][0];
                *(bf16x8*)&Hs[half][(r2 + 32) * 64 + sw] = sh[half][1];
                *(bf16x8*)&Ws[half][r2 * 64 + sw] = cat8(cvt4(sd[half][0]), cvt4(sd[half][1]));
                *(bf16x8*)&Ws[half][(r2 + 32) * 64 + sw] = cat8(cvt4(sd[half][2]), cvt4(sd[half][3]));
                int k2 = (tt + half + 2) * 64;
                if (k2 < HID) {
                    sh[half][0] = *(const bf16x8*)(h0 + k2);
                    sh[half][1] = *(const bf16x8*)(h1 + k2);
                    sd[half][0] = *(const f32x4*)(w0 + k2);
                    sd[half][1] = *(const f32x4*)(w0 + k2 + 4);
                    sd[half][2] = *(const f32x4*)(w1 + k2);
                    sd[half][3] = *(const f32x4*)(w1 + k2 + 4);
                }
                __syncthreads();
#pragma unroll
                for (int kk = 0; kk < 2; ++kk) {
                    int co = ((kk * 4 + fq) ^ (fr & 7)) * 8;
                    bf16x8 b = *(const bf16x8*)&Ws[half][(wn * 16 + fr) * 64 + co];
#pragma unroll
                    for (int ms = 0; ms < 4; ++ms) {
                        bf16x8 a = *(const bf16x8*)&Hs[half][(ms * 16 + fr) * 64 + co];
                        acc[ms] = __builtin_amdgcn_mfma_f32_16x16x32_bf16(a, b, acc[ms], 0, 0, 0);
                    }
                }
            }
        }

#pragma unroll
        for (int ms = 0; ms < 4; ++ms) {
#pragma unroll
            for (int reg = 0; reg < 4; ++reg) {
                int r = ms * 16 + fq * 4 + reg;
                if (r < rows) {
                    int slot = sl[m0 + r];
                    ybuf[(size_t)slot * DIM + dbase + wn * 16 + fr] = acc[ms][reg];
                }
            }
        }
    }
}

// ---------------- combine: out[t] = y[2t] + y[2t+1] ----------------
__global__ __launch_bounds__(256) void combine_kernel(const float* __restrict__ ybuf, float* __restrict__ out)
{
    int i = blockIdx.x * 256 + threadIdx.x;
    int t = i >> 8;
    int c = i & 255;
    const float4* ya = (const float4*)(ybuf + (size_t)(2 * t) * DIM) + c;
    const float4* yb = (const float4*)(ybuf + (size_t)(2 * t + 1) * DIM) + c;
    float4 a = *ya, b = *yb, r;
    r.x = a.x + b.x; r.y = a.y + b.y; r.z = a.z + b.z; r.w = a.w + b.w;
    ((float4*)(out + (size_t)t * DIM))[c] = r;
}

extern "C" void kernel_launch(void* const* d_in, const int* in_sizes, int n_in,
                              void* d_out, int out_size, void* d_ws, size_t ws_size,
                              hipStream_t stream) {
    const float* x  = (const float*)d_in[0];
    const float* rw = (const float*)d_in[1];
    const float* wg = (const float*)d_in[2];
    const float* wu = (const float*)d_in[3];
    const float* wd = (const float*)d_in[4];
    float* out = (float*)d_out;

    char* ws = (char*)d_ws;
    int* counts            = (int*)ws;                                   // 256 B
    int* slot_list         = (int*)(ws + 256);                           // 32 KB
    float* w_list          = (float*)(ws + 256 + NEXP * NTOK * 4);       // 32 KB
    __hip_bfloat16* xb     = (__hip_bfloat16*)(ws + 256 + 2 * NEXP * NTOK * 4);       // 2 MB
    __hip_bfloat16* h_buf  = (__hip_bfloat16*)((char*)xb + (size_t)NTOK * DIM * 2);   // 8 MB
    float* ybuf            = (float*)((char*)h_buf + (size_t)NTOK * TOPK * HID * 2);  // 8 MB
    __hip_bfloat16* zrow   = (__hip_bfloat16*)((char*)ybuf + (size_t)NTOK * TOPK * DIM * 4); // 4 KB zeros

    hipMemsetAsync(counts, 0, NEXP * sizeof(int), stream);
    hipMemsetAsync(zrow, 0, HID * sizeof(__hip_bfloat16), stream);
    router_kernel<<<NTOK, 64, 0, stream>>>(x, rw, xb, counts, slot_list, w_list);
    gateup_mfma<<<1024, 256, 0, stream>>>(xb, wg, wu, counts, slot_list, w_list, zrow, h_buf);
    down_mfma<<<512, 256, 0, stream>>>(h_buf, wd, counts, slot_list, zrow, ybuf);
    combine_kernel<<<NTOK * DIM / 4 / 256, 256, 0, stream>>>(ybuf, out);
}